// Round 10
// baseline (3463.629 us; speedup 1.0000x reference)
//
#include <hip/hip_runtime.h>

typedef unsigned short u16;
typedef unsigned int   u32;
typedef __bf16  bf16x8 __attribute__((ext_vector_type(8)));
typedef float   f32x4  __attribute__((ext_vector_type(4)));
typedef u16     u16x8  __attribute__((ext_vector_type(8)));

#define HID 2048
#define SEQ 2048
#define BB  4
#define NQH 8
#define HD_ 256
#define INTER_ 8192

__device__ __forceinline__ float b2f(u16 u) {
  union { float f; u32 i; } x; x.i = ((u32)u) << 16; return x.f;
}
__device__ __forceinline__ u16 f2b(float f) {
  u32 u = __float_as_uint(f);
  u32 r = u + 0x7fffu + ((u >> 16) & 1u);
  return (u16)(r >> 16);
}
__device__ __forceinline__ float wsum(float v) {
#pragma unroll
  for (int m = 1; m < 64; m <<= 1) v += __shfl_xor(v, m, 64);
  return v;
}
__device__ __forceinline__ float wmax(float v) {
#pragma unroll
  for (int m = 1; m < 64; m <<= 1) v = fmaxf(v, __shfl_xor(v, m, 64));
  return v;
}

// ---------------------------------------------------------------- sfac[b][n] = w[n]*(1 + dot(t[b], tw[n]))
__global__ __launch_bounds__(256) void scale_kernel(
    const float* __restrict__ temb,
    const float* __restrict__ w1, const float* __restrict__ tw1,
    const float* __restrict__ w2, const float* __restrict__ tw2,
    float* __restrict__ sf1, float* __restrict__ sf2) {
  const int wave = threadIdx.x >> 6, lane = threadIdx.x & 63;
  const int o = blockIdx.x * 4 + wave;
  const int set = o / (BB * HID);
  const int r = o % (BB * HID);
  const int b = r / HID, n = r % HID;
  const float* tw = set ? tw2 : tw1;
  const float* w  = set ? w2  : w1;
  float* sf       = set ? sf2 : sf1;
  const float* tv  = temb + (size_t)b * HID;
  const float* twr = tw + (size_t)n * HID;
  float acc = 0.f;
#pragma unroll
  for (int q = 0; q < 8; ++q) {
    const float4 a = *(const float4*)(tv + q * 256 + lane * 4);
    const float4 c = *(const float4*)(twr + q * 256 + lane * 4);
    acc += a.x * c.x + a.y * c.y + a.z * c.z + a.w * c.w;
  }
  acc = wsum(acc);
  if (lane == 0) sf[(size_t)b * HID + n] = w[n] * (1.0f + acc);
}

// ---------------------------------------------------------------- rope tables
__global__ __launch_bounds__(256) void rope_table_kernel(const int* __restrict__ pos_ids,
                                                         float* __restrict__ cosT,
                                                         float* __restrict__ sinT) {
  const int idx = blockIdx.x * 256 + threadIdx.x;   // B*S*128
  const int j = idx & 127, bs = idx >> 7;
  const float pos = (float)pos_ids[bs];
  const float inv = exp2f(-(float)j * (13.287712379549449f / 128.0f)); // 10000^{-j/128}
  const float ang = pos * inv;
  float sv, cv;
  sincosf(ang, &sv, &cv);
  cosT[idx] = cv; sinT[idx] = sv;
}

// ---------------------------------------------------------------- AdaRMS: bf16 out = fp32 in * rsqrt(mean sq) * sfac
__global__ __launch_bounds__(256) void rmsnorm_kernel(const float* __restrict__ xin,
                                                      const float* __restrict__ sfac,
                                                      u16* __restrict__ out) {
  const int row = blockIdx.x;
  const int b = row >> 11;
  const float* xr = xin + (size_t)row * HID + threadIdx.x * 8;
  const float4 v0 = *(const float4*)(xr);
  const float4 v1 = *(const float4*)(xr + 4);
  float v[8] = {v0.x, v0.y, v0.z, v0.w, v1.x, v1.y, v1.z, v1.w};
  float ss = 0.f;
#pragma unroll
  for (int j = 0; j < 8; ++j) ss += v[j] * v[j];
  ss = wsum(ss);
  __shared__ float red[4];
  const int wave = threadIdx.x >> 6, lane = threadIdx.x & 63;
  if (lane == 0) red[wave] = ss;
  __syncthreads();
  const float tot = red[0] + red[1] + red[2] + red[3];
  const float rs = rsqrtf(tot * (1.0f / HID) + 1e-6f);
  const float* sf = sfac + (size_t)b * HID + threadIdx.x * 8;
  u16* op = out + (size_t)row * HID + threadIdx.x * 8;
  u16x8 o;
#pragma unroll
  for (int j = 0; j < 8; ++j) o[j] = f2b(v[j] * rs * sf[j]);
  *(u16x8*)op = o;
}

// ---------------------------------------------------------------- MFMA GEMM: C(MxN) = A(MxK) @ B(NxK)^T, fp32 acc
// A bf16; B bf16 (BF32=false) or fp32 converted during staging (BF32=true).
// 128x128 tile, BK=32, 4 waves (2x2), reg-staged LDS. blockIdx.z offsets A by aZ, C by cZ elements.
// EPI: 0 = bf16 store; 1 = bf16 C := silu(C_old)*acc (in place);
//      2 = FP32 store acc + Res_f32[idx]; 3 = FP32 C := acc + C_old (in place residual)
template <int EPI, bool BF32>
__global__ __launch_bounds__(256) void gemm_bt(const u16* __restrict__ A,
                                               const void* __restrict__ Bv,
                                               const float* __restrict__ Res,
                                               void* __restrict__ Cv,
                                               int K, int lda, int ldb, int ldc,
                                               size_t aZ, size_t cZ) {
  A += blockIdx.z * aZ;
  __shared__ u16 As[128 * 32];
  __shared__ u16 Bs[128 * 32];
  const int m0 = blockIdx.x * 128, n0 = blockIdx.y * 128;
  const int wave = threadIdx.x >> 6, lane = threadIdx.x & 63;
  const int wr = wave >> 1, wc = wave & 1;
  const int l15 = lane & 15, l4 = lane >> 4;

  f32x4 acc[4][4] = {};

  for (int kt = 0; kt < K; kt += 32) {
#pragma unroll
    for (int j = 0; j < 2; ++j) {
      const int c = threadIdx.x + j * 256;      // 0..511
      const int row = c >> 2, col8 = (c & 3) << 3;
      const u16x8 av = *(const u16x8*)(A + (size_t)(m0 + row) * lda + kt + col8);
      *(u16x8*)(As + row * 32 + col8) = av;
      u16x8 bv;
      if constexpr (BF32) {
        const float* Bf = (const float*)Bv;
        const float4 f0 = *(const float4*)(Bf + (size_t)(n0 + row) * ldb + kt + col8);
        const float4 f1 = *(const float4*)(Bf + (size_t)(n0 + row) * ldb + kt + col8 + 4);
        bv[0]=f2b(f0.x); bv[1]=f2b(f0.y); bv[2]=f2b(f0.z); bv[3]=f2b(f0.w);
        bv[4]=f2b(f1.x); bv[5]=f2b(f1.y); bv[6]=f2b(f1.z); bv[7]=f2b(f1.w);
      } else {
        bv = *(const u16x8*)((const u16*)Bv + (size_t)(n0 + row) * ldb + kt + col8);
      }
      *(u16x8*)(Bs + row * 32 + col8) = bv;
    }
    __syncthreads();
    bf16x8 af[4], bf[4];
#pragma unroll
    for (int ms = 0; ms < 4; ++ms)
      af[ms] = *(const bf16x8*)(As + (wr * 64 + ms * 16 + l15) * 32 + l4 * 8);
#pragma unroll
    for (int ns = 0; ns < 4; ++ns)
      bf[ns] = *(const bf16x8*)(Bs + (wc * 64 + ns * 16 + l15) * 32 + l4 * 8);
#pragma unroll
    for (int ms = 0; ms < 4; ++ms)
#pragma unroll
      for (int ns = 0; ns < 4; ++ns)
        acc[ms][ns] = __builtin_amdgcn_mfma_f32_16x16x32_bf16(af[ms], bf[ns], acc[ms][ns], 0, 0, 0);
    __syncthreads();
  }

  u16* Cb = (u16*)Cv + blockIdx.z * cZ;
  float* Cf = (float*)Cv + blockIdx.z * cZ;
#pragma unroll
  for (int ms = 0; ms < 4; ++ms)
#pragma unroll
    for (int i = 0; i < 4; ++i) {
      const int row = m0 + wr * 64 + ms * 16 + l4 * 4 + i;
#pragma unroll
      for (int ns = 0; ns < 4; ++ns) {
        const int col = n0 + wc * 64 + ns * 16 + l15;
        const size_t idx = (size_t)row * ldc + col;
        const float v = acc[ms][ns][i];
        if constexpr (EPI == 0) {
          Cb[idx] = f2b(v);
        } else if constexpr (EPI == 1) {
          const float g = b2f(Cb[idx]);
          Cb[idx] = f2b(g / (1.0f + __expf(-g)) * v);
        } else if constexpr (EPI == 2) {
          Cf[idx] = v + Res[idx];
        } else {
          Cf[idx] = v + Cf[idx];
        }
      }
    }
}

// ---------------------------------------------------------------- RoPE in place (q scaled 1/16) + V transpose -> vt (b,d,s)
__global__ __launch_bounds__(256) void rope_apply_kernel(u16* __restrict__ qkv,
                                                         const float* __restrict__ cosT,
                                                         const float* __restrict__ sinT,
                                                         u16* __restrict__ vt) {
  const int tok = blockIdx.x;
  const int b = tok >> 11, s = tok & 2047;
  u16* rowp = qkv + (size_t)tok * 2560;
  const float* ct = cosT + (size_t)tok * 128;
  const float* st = sinT + (size_t)tok * 128;
  for (int p = threadIdx.x; p < 1024; p += 256) {
    const int h = p >> 7, j = p & 127;
    u16* e = rowp + h * 256 + j;
    const float x1 = b2f(e[0]), x2 = b2f(e[128]);
    const float c = ct[j], sn = st[j];
    e[0]   = f2b((x1 * c - x2 * sn) * 0.0625f);
    e[128] = f2b((x2 * c + x1 * sn) * 0.0625f);
  }
  if (threadIdx.x < 128) {
    const int j = threadIdx.x;
    u16* e = rowp + 2048 + j;
    const float x1 = b2f(e[0]), x2 = b2f(e[128]);
    const float c = ct[j], sn = st[j];
    e[0]   = f2b(x1 * c - x2 * sn);
    e[128] = f2b(x2 * c + x1 * sn);
  }
  {
    const int d = threadIdx.x;
    vt[((size_t)b * HD_ + d) * SEQ + s] = rowp[2304 + d];
  }
}

// ---------------------------------------------------------------- row softmax, in place, 2048-wide bf16 rows
__global__ __launch_bounds__(256) void softmax_kernel(u16* __restrict__ Sb) {
  const int row = blockIdx.x;
  u16* rp = Sb + (size_t)row * 2048 + threadIdx.x * 8;
  const u16x8 t = *(const u16x8*)rp;
  float v[8];
#pragma unroll
  for (int j = 0; j < 8; ++j) v[j] = b2f(t[j]);
  float m = v[0];
#pragma unroll
  for (int j = 1; j < 8; ++j) m = fmaxf(m, v[j]);
  m = wmax(m);
  __shared__ float redm[4], reds[4];
  const int wave = threadIdx.x >> 6, lane = threadIdx.x & 63;
  if (lane == 0) redm[wave] = m;
  __syncthreads();
  m = fmaxf(fmaxf(redm[0], redm[1]), fmaxf(redm[2], redm[3]));
  float s = 0.f;
#pragma unroll
  for (int j = 0; j < 8; ++j) { v[j] = __expf(v[j] - m); s += v[j]; }
  s = wsum(s);
  if (lane == 0) reds[wave] = s;
  __syncthreads();
  const float inv = 1.0f / (reds[0] + reds[1] + reds[2] + reds[3]);
  u16x8 o;
#pragma unroll
  for (int j = 0; j < 8; ++j) o[j] = f2b(v[j] * inv);
  *(u16x8*)rp = o;
}

// ---------------------------------------------------------------- launch
extern "C" void kernel_launch(void* const* d_in, const int* in_sizes, int n_in,
                              void* d_out, int out_size, void* d_ws, size_t ws_size,
                              hipStream_t stream) {
  const float* x     = (const float*)d_in[0];
  const int*   pos   = (const int*)d_in[1];
  const float* temb  = (const float*)d_in[2];
  const float* ln1w  = (const float*)d_in[3];
  const float* ln1tw = (const float*)d_in[4];
  const float* ln2w  = (const float*)d_in[5];
  const float* ln2tw = (const float*)d_in[6];
  const float* Wq    = (const float*)d_in[7];
  const float* Wk    = (const float*)d_in[8];
  const float* Wv    = (const float*)d_in[9];
  const float* Wo    = (const float*)d_in[10];
  const float* Wg    = (const float*)d_in[11];
  const float* Wu    = (const float*)d_in[12];
  const float* Wd    = (const float*)d_in[13];
  float* out = (float*)d_out;      // OUTPUT IS FP32

  char* ws = (char*)d_ws;
  // ---- workspace layout (bytes); REQUIRED = 155,320,320 (148.1 MiB)
  constexpr size_t OFF_SF1  = 0;          // 32 KB
  constexpr size_t OFF_SF2  = 32768;      // 32 KB
  constexpr size_t OFF_H    = 131072;     // 33,554,432
  constexpr size_t OFF_QKV  = 33685504;   // 41,943,040
  constexpr size_t OFF_VT   = 75628544;   //  4,194,304
  constexpr size_t OFF_COS  = 79822848;   //  4,194,304
  constexpr size_t OFF_SIN  = 84017152;   //  4,194,304
  constexpr size_t OFF_CTX  = 88211456;   // 33,554,432
  constexpr size_t OFF_POOL = 121765888;  // 33,554,432: Sbuf (4 heads) / —
  constexpr size_t OFF_INT  = OFF_QKV;    // MLP inter chunk aliases dead qkv (33.5MB <= 42MB)
  constexpr size_t REQUIRED = OFF_POOL + 33554432;

  float* sf1 = (float*)(ws + OFF_SF1);
  float* sf2 = (float*)(ws + OFF_SF2);
  u16* hbuf = (u16*)(ws + OFF_H);
  u16* qkv  = (u16*)(ws + OFF_QKV);
  u16* vt   = (u16*)(ws + OFF_VT);
  float* cosT = (float*)(ws + OFF_COS);
  float* sinT = (float*)(ws + OFF_SIN);
  u16* ctx  = (u16*)(ws + OFF_CTX);
  u16* Sbuf = (u16*)(ws + OFF_POOL);
  u16* inter = (u16*)(ws + OFF_INT);

  if (ws_size < REQUIRED) return;

  // 1) adaptive scales + rope tables
  scale_kernel<<<(2 * BB * HID) / 4, 256, 0, stream>>>(temb, ln1w, ln1tw, ln2w, ln2tw, sf1, sf2);
  rope_table_kernel<<<(BB * SEQ * 128) / 256, 256, 0, stream>>>(pos, cosT, sinT);

  // 2) norm1 -> h (bf16)
  rmsnorm_kernel<<<BB * SEQ, 256, 0, stream>>>(x, sf1, hbuf);

  // 3) q/k/v projections (fp32 weights converted during staging)
  gemm_bt<0, true><<<dim3(64, 16), 256, 0, stream>>>(hbuf, Wq, nullptr, qkv,        HID, HID, HID, 2560, 0, 0);
  gemm_bt<0, true><<<dim3(64, 2),  256, 0, stream>>>(hbuf, Wk, nullptr, qkv + 2048, HID, HID, HID, 2560, 0, 0);
  gemm_bt<0, true><<<dim3(64, 2),  256, 0, stream>>>(hbuf, Wv, nullptr, qkv + 2304, HID, HID, HID, 2560, 0, 0);

  // 4) rope in place (q scaled 1/16), v -> vt
  rope_apply_kernel<<<BB * SEQ, 256, 0, stream>>>(qkv, cosT, sinT, vt);

  // 5) attention: per batch, 4 heads per launch via blockIdx.z
  for (int b = 0; b < BB; ++b) {
    const u16* kb = qkv + (size_t)b * SEQ * 2560 + 2048;
    const u16* vb = vt + (size_t)b * HD_ * SEQ;
    for (int half = 0; half < 2; ++half) {
      const u16* qh = qkv + (size_t)b * SEQ * 2560 + half * 4 * HD_;
      u16* ch = ctx + (size_t)b * SEQ * HID + half * 4 * HD_;
      gemm_bt<0, false><<<dim3(16, 16, 4), 256, 0, stream>>>(
          qh, kb, nullptr, Sbuf, HD_, 2560, 2560, SEQ, (size_t)HD_, (size_t)SEQ * SEQ);
      softmax_kernel<<<4 * SEQ, 256, 0, stream>>>(Sbuf);
      gemm_bt<0, false><<<dim3(16, 2, 4), 256, 0, stream>>>(
          Sbuf, vb, nullptr, ch, SEQ, SEQ, SEQ, HID, (size_t)SEQ * SEQ, (size_t)HD_);
    }
  }

  // 6) x2 = ctx @ Wo^T + x -> out (FP32)
  gemm_bt<2, true><<<dim3(64, 16), 256, 0, stream>>>(ctx, Wo, x, out, HID, HID, HID, HID, 0, 0);

  // 7) norm2 -> h (reads fp32 x2)
  rmsnorm_kernel<<<BB * SEQ, 256, 0, stream>>>(out, sf2, hbuf);

  // 8) MLP, 4 chunks of M=2048 (inter aliases dead qkv)
  constexpr int MC = BB * SEQ / 4;
  for (int c = 0; c < 4; ++c) {
    const u16* hA = hbuf + (size_t)c * MC * HID;
    float* outC = out + (size_t)c * MC * HID;
    gemm_bt<0, true><<<dim3(MC / 128, INTER_ / 128), 256, 0, stream>>>(hA, Wg, nullptr, inter, HID, HID, HID, INTER_, 0, 0);
    gemm_bt<1, true><<<dim3(MC / 128, INTER_ / 128), 256, 0, stream>>>(hA, Wu, nullptr, inter, HID, HID, HID, INTER_, 0, 0);
    gemm_bt<3, true><<<dim3(MC / 128, HID / 128),    256, 0, stream>>>(inter, Wd, nullptr, outC, INTER_, INTER_, INTER_, HID, 0, 0);
  }

  (void)in_sizes; (void)n_in; (void)out_size;
}

// Round 11
// 3462.606 us; speedup vs baseline: 1.0003x; 1.0003x over previous
//
#include <hip/hip_runtime.h>

typedef unsigned short u16;
typedef unsigned int   u32;
typedef __bf16  bf16x8 __attribute__((ext_vector_type(8)));
typedef float   f32x4  __attribute__((ext_vector_type(4)));
typedef u16     u16x4  __attribute__((ext_vector_type(4)));
typedef u16     u16x8  __attribute__((ext_vector_type(8)));

#define HID 2048
#define SEQ 2048
#define BB  4
#define NQH 8
#define HD_ 256
#define INTER_ 8192

__device__ __forceinline__ float b2f(u16 u) {
  union { float f; u32 i; } x; x.i = ((u32)u) << 16; return x.f;
}
__device__ __forceinline__ u16 f2b(float f) {
  u32 u = __float_as_uint(f);
  u32 r = u + 0x7fffu + ((u >> 16) & 1u);
  return (u16)(r >> 16);
}
__device__ __forceinline__ float wsum(float v) {
#pragma unroll
  for (int m = 1; m < 64; m <<= 1) v += __shfl_xor(v, m, 64);
  return v;
}
__device__ __forceinline__ void gload_lds16(const void* gp, void* lp) {
  __builtin_amdgcn_global_load_lds(
      (const __attribute__((address_space(1))) void*)gp,
      (__attribute__((address_space(3))) void*)lp, 16, 0, 0);
}

// ---------------------------------------------------------------- fp32 -> bf16 convert
__global__ __launch_bounds__(256) void cvt_kernel(const float* __restrict__ src,
                                                  u16* __restrict__ dst, int n4) {
  int i = blockIdx.x * 256 + threadIdx.x;
  if (i < n4) {
    const float4 v = *(const float4*)(src + (size_t)i * 4);
    u16x4 o;
    o[0] = f2b(v.x); o[1] = f2b(v.y); o[2] = f2b(v.z); o[3] = f2b(v.w);
    *(u16x4*)(dst + (size_t)i * 4) = o;
  }
}

// ---------------------------------------------------------------- sfac[b][n] = w[n]*(1 + dot(t[b], tw[n]))
__global__ __launch_bounds__(256) void scale_kernel(
    const float* __restrict__ temb,
    const float* __restrict__ w1, const float* __restrict__ tw1,
    const float* __restrict__ w2, const float* __restrict__ tw2,
    float* __restrict__ sf1, float* __restrict__ sf2) {
  const int wave = threadIdx.x >> 6, lane = threadIdx.x & 63;
  const int o = blockIdx.x * 4 + wave;
  const int set = o / (BB * HID);
  const int r = o % (BB * HID);
  const int b = r / HID, n = r % HID;
  const float* tw = set ? tw2 : tw1;
  const float* w  = set ? w2  : w1;
  float* sf       = set ? sf2 : sf1;
  const float* tv  = temb + (size_t)b * HID;
  const float* twr = tw + (size_t)n * HID;
  float acc = 0.f;
#pragma unroll
  for (int q = 0; q < 8; ++q) {
    const float4 a = *(const float4*)(tv + q * 256 + lane * 4);
    const float4 c = *(const float4*)(twr + q * 256 + lane * 4);
    acc += a.x * c.x + a.y * c.y + a.z * c.z + a.w * c.w;
  }
  acc = wsum(acc);
  if (lane == 0) sf[(size_t)b * HID + n] = w[n] * (1.0f + acc);
}

// ---------------------------------------------------------------- rope tables
__global__ __launch_bounds__(256) void rope_table_kernel(const int* __restrict__ pos_ids,
                                                         float* __restrict__ cosT,
                                                         float* __restrict__ sinT) {
  const int idx = blockIdx.x * 256 + threadIdx.x;   // B*S*128
  const int j = idx & 127, bs = idx >> 7;
  const float pos = (float)pos_ids[bs];
  const float inv = exp2f(-(float)j * (13.287712379549449f / 128.0f)); // 10000^{-j/128}
  const float ang = pos * inv;
  float sv, cv;
  sincosf(ang, &sv, &cv);
  cosT[idx] = cv; sinT[idx] = sv;
}

// ---------------------------------------------------------------- AdaRMS: bf16 out = fp32 in * rsqrt(mean sq) * sfac
__global__ __launch_bounds__(256) void rmsnorm_kernel(const float* __restrict__ xin,
                                                      const float* __restrict__ sfac,
                                                      u16* __restrict__ out) {
  const int row = blockIdx.x;
  const int b = row >> 11;
  const float* xr = xin + (size_t)row * HID + threadIdx.x * 8;
  const float4 v0 = *(const float4*)(xr);
  const float4 v1 = *(const float4*)(xr + 4);
  float v[8] = {v0.x, v0.y, v0.z, v0.w, v1.x, v1.y, v1.z, v1.w};
  float ss = 0.f;
#pragma unroll
  for (int j = 0; j < 8; ++j) ss += v[j] * v[j];
  ss = wsum(ss);
  __shared__ float red[4];
  const int wave = threadIdx.x >> 6, lane = threadIdx.x & 63;
  if (lane == 0) red[wave] = ss;
  __syncthreads();
  const float tot = red[0] + red[1] + red[2] + red[3];
  const float rs = rsqrtf(tot * (1.0f / HID) + 1e-6f);
  const float* sf = sfac + (size_t)b * HID + threadIdx.x * 8;
  u16* op = out + (size_t)row * HID + threadIdx.x * 8;
  u16x8 o;
#pragma unroll
  for (int j = 0; j < 8; ++j) o[j] = f2b(v[j] * rs * sf[j]);
  *(u16x8*)op = o;
}

// ---------------------------------------------------------------- MFMA GEMM: C(MxN) = A(MxK) @ B(NxK)^T, bf16 in, fp32 acc
// m97 structure: 128x128 tile, BK=32, 4 waves (2x2), global_load_lds width-16 staging.
// EPI: 0 = bf16 store; 1 = bf16 C := silu(C_old)*acc (in place);
//      2 = FP32 store acc + Res_f32[idx]; 3 = FP32 C := acc + C_old (in place residual)
template <int EPI>
__global__ __launch_bounds__(256) void gemm_bt(const u16* __restrict__ A,
                                               const u16* __restrict__ B,
                                               const float* __restrict__ Res,
                                               void* __restrict__ Cv,
                                               int K, int lda, int ldb, int ldc) {
  __shared__ u16 As[128 * 32];
  __shared__ u16 Bs[128 * 32];
  const int m0 = blockIdx.x * 128, n0 = blockIdx.y * 128;
  const int wave = threadIdx.x >> 6, lane = threadIdx.x & 63;
  const int wr = wave >> 1, wc = wave & 1;
  const int l15 = lane & 15, l4 = lane >> 4;

  f32x4 acc[4][4] = {};

  for (int kt = 0; kt < K; kt += 32) {
#pragma unroll
    for (int j = 0; j < 2; ++j) {
      const int c = threadIdx.x + j * 256;      // 0..511
      const int row = c >> 2, col8 = (c & 3) << 3;
      gload_lds16(A + (size_t)(m0 + row) * lda + kt + col8, As + c * 8);
      gload_lds16(B + (size_t)(n0 + row) * ldb + kt + col8, Bs + c * 8);
    }
    __syncthreads();
    bf16x8 af[4], bf[4];
#pragma unroll
    for (int ms = 0; ms < 4; ++ms)
      af[ms] = *(const bf16x8*)(As + (wr * 64 + ms * 16 + l15) * 32 + l4 * 8);
#pragma unroll
    for (int ns = 0; ns < 4; ++ns)
      bf[ns] = *(const bf16x8*)(Bs + (wc * 64 + ns * 16 + l15) * 32 + l4 * 8);
#pragma unroll
    for (int ms = 0; ms < 4; ++ms)
#pragma unroll
      for (int ns = 0; ns < 4; ++ns)
        acc[ms][ns] = __builtin_amdgcn_mfma_f32_16x16x32_bf16(af[ms], bf[ns], acc[ms][ns], 0, 0, 0);
    __syncthreads();
  }

  u16* Cb = (u16*)Cv;
  float* Cf = (float*)Cv;
#pragma unroll
  for (int ms = 0; ms < 4; ++ms)
#pragma unroll
    for (int i = 0; i < 4; ++i) {
      const int row = m0 + wr * 64 + ms * 16 + l4 * 4 + i;
#pragma unroll
      for (int ns = 0; ns < 4; ++ns) {
        const int col = n0 + wc * 64 + ns * 16 + l15;
        const size_t idx = (size_t)row * ldc + col;
        const float v = acc[ms][ns][i];
        if constexpr (EPI == 0) {
          Cb[idx] = f2b(v);
        } else if constexpr (EPI == 1) {
          const float g = b2f(Cb[idx]);
          Cb[idx] = f2b(g / (1.0f + __expf(-g)) * v);
        } else if constexpr (EPI == 2) {
          Cf[idx] = v + Res[idx];
        } else {
          Cf[idx] = v + Cf[idx];
        }
      }
    }
}

// ---------------------------------------------------------------- RoPE in place (q scaled 1/16) + V transpose -> vt (b,d,s)
__global__ __launch_bounds__(256) void rope_apply_kernel(u16* __restrict__ qkv,
                                                         const float* __restrict__ cosT,
                                                         const float* __restrict__ sinT,
                                                         u16* __restrict__ vt) {
  const int tok = blockIdx.x;
  const int b = tok >> 11, s = tok & 2047;
  u16* rowp = qkv + (size_t)tok * 2560;
  const float* ct = cosT + (size_t)tok * 128;
  const float* st = sinT + (size_t)tok * 128;
  for (int p = threadIdx.x; p < 1024; p += 256) {
    const int h = p >> 7, j = p & 127;
    u16* e = rowp + h * 256 + j;
    const float x1 = b2f(e[0]), x2 = b2f(e[128]);
    const float c = ct[j], sn = st[j];
    e[0]   = f2b((x1 * c - x2 * sn) * 0.0625f);
    e[128] = f2b((x2 * c + x1 * sn) * 0.0625f);
  }
  if (threadIdx.x < 128) {
    const int j = threadIdx.x;
    u16* e = rowp + 2048 + j;
    const float x1 = b2f(e[0]), x2 = b2f(e[128]);
    const float c = ct[j], sn = st[j];
    e[0]   = f2b(x1 * c - x2 * sn);
    e[128] = f2b(x2 * c + x1 * sn);
  }
  {
    const int d = threadIdx.x;
    vt[((size_t)b * HD_ + d) * SEQ + s] = rowp[2304 + d];
  }
}

// ---------------------------------------------------------------- fused flash attention (non-causal), GQA NKV=1
// grid: (b*8+h)*32 + qtile ; 4 waves x 16 q-rows each; K/V streamed from L2/L3
__global__ __launch_bounds__(256) void attn_kernel(const u16* __restrict__ qkv,
                                                   const u16* __restrict__ Vt,
                                                   u16* __restrict__ Ctx) {
  const int blk = blockIdx.x;
  const int qt = blk & 31, bh = blk >> 5, h = bh & 7, b = bh >> 3;
  const int wave = threadIdx.x >> 6, lane = threadIdx.x & 63;
  const int l15 = lane & 15, l4 = lane >> 4;
  __shared__ float Pl[4][16][64];
  float* pw = &Pl[wave][0][0];

  const u16* qp = qkv + ((size_t)b * SEQ + qt * 64 + wave * 16 + l15) * 2560 + h * 256 + l4 * 8;
  bf16x8 qf[8];
#pragma unroll
  for (int kk = 0; kk < 8; ++kk) qf[kk] = *(const bf16x8*)(qp + kk * 32);

  f32x4 ctx[16] = {};
  float m_run[4] = {-1e30f, -1e30f, -1e30f, -1e30f};
  float l_run[4] = {};

  const u16* kb0 = qkv + (size_t)b * SEQ * 2560 + 2048;
  const u16* vb0 = Vt + (size_t)b * HD_ * SEQ;

  for (int kt = 0; kt < 32; ++kt) {
    f32x4 sc[4] = {};
#pragma unroll
    for (int sub = 0; sub < 4; ++sub) {
      const u16* kp = kb0 + (size_t)(kt * 64 + sub * 16 + l15) * 2560 + l4 * 8;
#pragma unroll
      for (int kk = 0; kk < 8; ++kk) {
        const bf16x8 kf = *(const bf16x8*)(kp + kk * 32);
        sc[sub] = __builtin_amdgcn_mfma_f32_16x16x32_bf16(qf[kk], kf, sc[sub], 0, 0, 0);
      }
    }
    float al[4];
#pragma unroll
    for (int i = 0; i < 4; ++i) {
      float tm = fmaxf(fmaxf(sc[0][i], sc[1][i]), fmaxf(sc[2][i], sc[3][i]));
      tm = fmaxf(tm, __shfl_xor(tm, 1, 64));
      tm = fmaxf(tm, __shfl_xor(tm, 2, 64));
      tm = fmaxf(tm, __shfl_xor(tm, 4, 64));
      tm = fmaxf(tm, __shfl_xor(tm, 8, 64));
      const float mn = fmaxf(m_run[i], tm);
      al[i] = __expf(m_run[i] - mn);
      m_run[i] = mn;
      float r = 0.f;
#pragma unroll
      for (int sub = 0; sub < 4; ++sub) { sc[sub][i] = __expf(sc[sub][i] - mn); r += sc[sub][i]; }
      r += __shfl_xor(r, 1, 64);
      r += __shfl_xor(r, 2, 64);
      r += __shfl_xor(r, 4, 64);
      r += __shfl_xor(r, 8, 64);
      l_run[i] = l_run[i] * al[i] + r;
    }
#pragma unroll
    for (int n = 0; n < 16; ++n) {
      ctx[n][0] *= al[0]; ctx[n][1] *= al[1]; ctx[n][2] *= al[2]; ctx[n][3] *= al[3];
    }
    // P -> wave-private LDS to redistribute into A-fragment layout
#pragma unroll
    for (int sub = 0; sub < 4; ++sub)
#pragma unroll
      for (int i = 0; i < 4; ++i)
        pw[(l4 * 4 + i) * 64 + sub * 16 + l15] = sc[sub][i];
    __threadfence_block();
#pragma unroll
    for (int kk2 = 0; kk2 < 2; ++kk2) {
      const f32x4 p0 = *(const f32x4*)(pw + l15 * 64 + kk2 * 32 + l4 * 8);
      const f32x4 p1 = *(const f32x4*)(pw + l15 * 64 + kk2 * 32 + l4 * 8 + 4);
      bf16x8 pa;
      pa[0] = (__bf16)p0[0]; pa[1] = (__bf16)p0[1]; pa[2] = (__bf16)p0[2]; pa[3] = (__bf16)p0[3];
      pa[4] = (__bf16)p1[0]; pa[5] = (__bf16)p1[1]; pa[6] = (__bf16)p1[2]; pa[7] = (__bf16)p1[3];
      const u16* vp = vb0 + (size_t)l15 * SEQ + kt * 64 + kk2 * 32 + l4 * 8;
#pragma unroll
      for (int n = 0; n < 16; ++n) {
        const bf16x8 vf = *(const bf16x8*)(vp + (size_t)n * 16 * SEQ);
        ctx[n] = __builtin_amdgcn_mfma_f32_16x16x32_bf16(pa, vf, ctx[n], 0, 0, 0);
      }
    }
    __threadfence_block();
  }
  float inv[4];
#pragma unroll
  for (int i = 0; i < 4; ++i) inv[i] = 1.0f / l_run[i];
  const size_t srow = (size_t)b * SEQ + qt * 64 + wave * 16 + l4 * 4;
#pragma unroll
  for (int i = 0; i < 4; ++i) {
    u16* cp = Ctx + (srow + i) * (NQH * HD_) + h * HD_ + l15;
#pragma unroll
    for (int n = 0; n < 16; ++n) cp[n * 16] = f2b(ctx[n][i] * inv[i]);
  }
}

// ---------------------------------------------------------------- launch
extern "C" void kernel_launch(void* const* d_in, const int* in_sizes, int n_in,
                              void* d_out, int out_size, void* d_ws, size_t ws_size,
                              hipStream_t stream) {
  const float* x     = (const float*)d_in[0];
  const int*   pos   = (const int*)d_in[1];
  const float* temb  = (const float*)d_in[2];
  const float* ln1w  = (const float*)d_in[3];
  const float* ln1tw = (const float*)d_in[4];
  const float* ln2w  = (const float*)d_in[5];
  const float* ln2tw = (const float*)d_in[6];
  const float* Wq    = (const float*)d_in[7];
  const float* Wk    = (const float*)d_in[8];
  const float* Wv    = (const float*)d_in[9];
  const float* Wo    = (const float*)d_in[10];
  const float* Wg    = (const float*)d_in[11];
  const float* Wu    = (const float*)d_in[12];
  const float* Wd    = (const float*)d_in[13];
  float* out = (float*)d_out;      // fp32 output

  char* ws = (char*)d_ws;
  // ---- workspace layout (bytes); REQUIRED = 241,238,016 (230.06 MiB; 254.06 MiB proven safe in R3)
  constexpr size_t OFF_SF1  = 0;
  constexpr size_t OFF_SF2  = 32768;
  constexpr size_t OFF_COS  = 65536;        //  4,194,304
  constexpr size_t OFF_SIN  = 4259840;      //  4,194,304
  constexpr size_t OFF_WQKV = 8454144;      // 10,485,760
  constexpr size_t OFF_WO   = 18939904;     //  8,388,608
  constexpr size_t OFF_WG   = 27328512;     // 33,554,432
  constexpr size_t OFF_WU   = 60882944;     // 33,554,432
  constexpr size_t OFF_WD   = 94437376;     // 33,554,432
  constexpr size_t OFF_H    = 127991808;    // 33,554,432
  constexpr size_t OFF_QKV  = 161546240;    // 41,943,040 (inter aliases during MLP)
  constexpr size_t OFF_VT   = 203489280;    //  4,194,304
  constexpr size_t OFF_CTX  = 207683584;    // 33,554,432
  constexpr size_t REQUIRED = 241238016;

  float* sf1 = (float*)(ws + OFF_SF1);
  float* sf2 = (float*)(ws + OFF_SF2);
  float* cosT = (float*)(ws + OFF_COS);
  float* sinT = (float*)(ws + OFF_SIN);
  u16* wqkv = (u16*)(ws + OFF_WQKV);
  u16* wo   = (u16*)(ws + OFF_WO);
  u16* wg   = (u16*)(ws + OFF_WG);
  u16* wu   = (u16*)(ws + OFF_WU);
  u16* wd   = (u16*)(ws + OFF_WD);
  u16* hbuf = (u16*)(ws + OFF_H);
  u16* qkv  = (u16*)(ws + OFF_QKV);
  u16* vt   = (u16*)(ws + OFF_VT);
  u16* ctx  = (u16*)(ws + OFF_CTX);
  u16* inter = (u16*)(ws + OFF_QKV);

  if (ws_size < REQUIRED) return;

  auto cvt = [&](const float* s, u16* d, size_t n) {
    int n4 = (int)(n / 4);
    cvt_kernel<<<(n4 + 255) / 256, 256, 0, stream>>>(s, d, n4);
  };

  // 0) all weights -> bf16 once
  cvt(Wq, wqkv,                      (size_t)2048 * HID);
  cvt(Wk, wqkv + (size_t)2048 * HID, (size_t)256 * HID);
  cvt(Wv, wqkv + (size_t)2304 * HID, (size_t)256 * HID);
  cvt(Wo, wo, (size_t)HID * HID);
  cvt(Wg, wg, (size_t)INTER_ * HID);
  cvt(Wu, wu, (size_t)INTER_ * HID);
  cvt(Wd, wd, (size_t)HID * INTER_);

  // 1) adaptive scales + rope tables
  scale_kernel<<<(2 * BB * HID) / 4, 256, 0, stream>>>(temb, ln1w, ln1tw, ln2w, ln2tw, sf1, sf2);
  rope_table_kernel<<<(BB * SEQ * 128) / 256, 256, 0, stream>>>(pos, cosT, sinT);

  // 2) norm1 -> h (bf16)
  rmsnorm_kernel<<<BB * SEQ, 256, 0, stream>>>(x, sf1, hbuf);

  // 3) qkv = h @ Wqkv^T
  gemm_bt<0><<<dim3(64, 20), 256, 0, stream>>>(hbuf, wqkv, nullptr, qkv, HID, HID, HID, 2560);

  // 4) rope in place (q scaled 1/16), v -> vt
  rope_apply_kernel<<<BB * SEQ, 256, 0, stream>>>(qkv, cosT, sinT, vt);

  // 5) fused flash attention -> ctx (b,s,h*d)
  attn_kernel<<<BB * NQH * (SEQ / 64), 256, 0, stream>>>(qkv, vt, ctx);

  // 6) x2 = ctx @ Wo^T + x -> out (fp32)
  gemm_bt<2><<<dim3(64, 16), 256, 0, stream>>>(ctx, wo, x, out, HID, HID, HID, HID);

  // 7) norm2 -> h (reads fp32 x2)
  rmsnorm_kernel<<<BB * SEQ, 256, 0, stream>>>(out, sf2, hbuf);

  // 8) MLP, 4 chunks of M=2048 (inter aliases dead qkv)
  constexpr int MC = BB * SEQ / 4;
  for (int c = 0; c < 4; ++c) {
    const u16* hA = hbuf + (size_t)c * MC * HID;
    float* outC = out + (size_t)c * MC * HID;
    gemm_bt<0><<<dim3(MC / 128, INTER_ / 128), 256, 0, stream>>>(hA, wg, nullptr, inter, HID, HID, HID, INTER_);
    gemm_bt<1><<<dim3(MC / 128, INTER_ / 128), 256, 0, stream>>>(hA, wu, nullptr, inter, HID, HID, HID, INTER_);
    gemm_bt<3><<<dim3(MC / 128, HID / 128),    256, 0, stream>>>(inter, wd, nullptr, outC, INTER_, INTER_, INTER_, HID);
  }

  (void)in_sizes; (void)n_in; (void)out_size;
}

// Round 12
// 2483.982 us; speedup vs baseline: 1.3944x; 1.3940x over previous
//
#include <hip/hip_runtime.h>

typedef unsigned short u16;
typedef unsigned int   u32;
typedef __bf16  bf16x8 __attribute__((ext_vector_type(8)));
typedef float   f32x4  __attribute__((ext_vector_type(4)));
typedef u16     u16x4  __attribute__((ext_vector_type(4)));
typedef u16     u16x8  __attribute__((ext_vector_type(8)));

#define HID 2048
#define SEQ 2048
#define BB  4
#define NQH 8
#define HD_ 256
#define INTER_ 8192

__device__ __forceinline__ float b2f(u16 u) {
  union { float f; u32 i; } x; x.i = ((u32)u) << 16; return x.f;
}
__device__ __forceinline__ u16 f2b(float f) {
  u32 u = __float_as_uint(f);
  u32 r = u + 0x7fffu + ((u >> 16) & 1u);
  return (u16)(r >> 16);
}
__device__ __forceinline__ float wsum(float v) {
#pragma unroll
  for (int m = 1; m < 64; m <<= 1) v += __shfl_xor(v, m, 64);
  return v;
}
__device__ __forceinline__ float wmax(float v) {
#pragma unroll
  for (int m = 1; m < 64; m <<= 1) v = fmaxf(v, __shfl_xor(v, m, 64));
  return v;
}
__device__ __forceinline__ void gload_lds16(const void* gp, void* lp) {
  __builtin_amdgcn_global_load_lds(
      (const __attribute__((address_space(1))) void*)gp,
      (__attribute__((address_space(3))) void*)lp, 16, 0, 0);
}
// XCD-aware block swizzle (nwg % 8 == 0 on all our grids): XCD k gets a
// contiguous chunk of tiles -> L2 locality on shared operand panels.
__device__ __forceinline__ void xcd_swizzle(int& bx, int& by) {
  const int nx = gridDim.x, ny = gridDim.y;
  const int nwg = nx * ny;
  if ((nwg & 7) == 0) {
    const int orig = by * nx + bx;
    const int q = nwg >> 3;
    const int wg = (orig & 7) * q + (orig >> 3);
    bx = wg % nx; by = wg / nx;
  }
}

// ---------------------------------------------------------------- fp32 -> bf16 convert
__global__ __launch_bounds__(256) void cvt_kernel(const float* __restrict__ src,
                                                  u16* __restrict__ dst, int n4) {
  int i = blockIdx.x * 256 + threadIdx.x;
  if (i < n4) {
    const float4 v = *(const float4*)(src + (size_t)i * 4);
    u16x4 o;
    o[0] = f2b(v.x); o[1] = f2b(v.y); o[2] = f2b(v.z); o[3] = f2b(v.w);
    *(u16x4*)(dst + (size_t)i * 4) = o;
  }
}

// ---------------------------------------------------------------- sfac[b][n] = w[n]*(1 + dot(t[b], tw[n]))
__global__ __launch_bounds__(256) void scale_kernel(
    const float* __restrict__ temb,
    const float* __restrict__ w1, const float* __restrict__ tw1,
    const float* __restrict__ w2, const float* __restrict__ tw2,
    float* __restrict__ sf1, float* __restrict__ sf2) {
  const int wave = threadIdx.x >> 6, lane = threadIdx.x & 63;
  const int o = blockIdx.x * 4 + wave;
  const int set = o / (BB * HID);
  const int r = o % (BB * HID);
  const int b = r / HID, n = r % HID;
  const float* tw = set ? tw2 : tw1;
  const float* w  = set ? w2  : w1;
  float* sf       = set ? sf2 : sf1;
  const float* tv  = temb + (size_t)b * HID;
  const float* twr = tw + (size_t)n * HID;
  float acc = 0.f;
#pragma unroll
  for (int q = 0; q < 8; ++q) {
    const float4 a = *(const float4*)(tv + q * 256 + lane * 4);
    const float4 c = *(const float4*)(twr + q * 256 + lane * 4);
    acc += a.x * c.x + a.y * c.y + a.z * c.z + a.w * c.w;
  }
  acc = wsum(acc);
  if (lane == 0) sf[(size_t)b * HID + n] = w[n] * (1.0f + acc);
}

// ---------------------------------------------------------------- rope tables
__global__ __launch_bounds__(256) void rope_table_kernel(const int* __restrict__ pos_ids,
                                                         float* __restrict__ cosT,
                                                         float* __restrict__ sinT) {
  const int idx = blockIdx.x * 256 + threadIdx.x;   // B*S*128
  const int j = idx & 127, bs = idx >> 7;
  const float pos = (float)pos_ids[bs];
  const float inv = exp2f(-(float)j * (13.287712379549449f / 128.0f)); // 10000^{-j/128}
  const float ang = pos * inv;
  float sv, cv;
  sincosf(ang, &sv, &cv);
  cosT[idx] = cv; sinT[idx] = sv;
}

// ---------------------------------------------------------------- AdaRMS: bf16 out = fp32 in * rsqrt(mean sq) * sfac
__global__ __launch_bounds__(256) void rmsnorm_kernel(const float* __restrict__ xin,
                                                      const float* __restrict__ sfac,
                                                      u16* __restrict__ out) {
  const int row = blockIdx.x;
  const int b = row >> 11;
  const float* xr = xin + (size_t)row * HID + threadIdx.x * 8;
  const float4 v0 = *(const float4*)(xr);
  const float4 v1 = *(const float4*)(xr + 4);
  float v[8] = {v0.x, v0.y, v0.z, v0.w, v1.x, v1.y, v1.z, v1.w};
  float ss = 0.f;
#pragma unroll
  for (int j = 0; j < 8; ++j) ss += v[j] * v[j];
  ss = wsum(ss);
  __shared__ float red[4];
  const int wave = threadIdx.x >> 6, lane = threadIdx.x & 63;
  if (lane == 0) red[wave] = ss;
  __syncthreads();
  const float tot = red[0] + red[1] + red[2] + red[3];
  const float rs = rsqrtf(tot * (1.0f / HID) + 1e-6f);
  const float* sf = sfac + (size_t)b * HID + threadIdx.x * 8;
  u16* op = out + (size_t)row * HID + threadIdx.x * 8;
  u16x8 o;
#pragma unroll
  for (int j = 0; j < 8; ++j) o[j] = f2b(v[j] * rs * sf[j]);
  *(u16x8*)op = o;
}

// ---------------------------------------------------------------- MFMA GEMM: C(MxN) = A(MxK) @ B(NxK)^T, bf16 in, fp32 acc
// m97 structure: 128x128 tile, BK=32, 4 waves (2x2), global_load_lds width-16 staging,
// XCD-aware block swizzle. blockIdx.z offsets A by aZ, C by cZ elements.
// EPI: 0 = bf16 store; 1 = bf16 C := silu(C_old)*acc (in place);
//      2 = FP32 store acc + Res_f32[idx]; 3 = FP32 C := acc + C_old (in place residual)
template <int EPI>
__global__ __launch_bounds__(256) void gemm_bt(const u16* __restrict__ A,
                                               const u16* __restrict__ B,
                                               const float* __restrict__ Res,
                                               void* __restrict__ Cv,
                                               int K, int lda, int ldb, int ldc,
                                               size_t aZ, size_t cZ) {
  A += blockIdx.z * aZ;
  __shared__ u16 As[128 * 32];
  __shared__ u16 Bs[128 * 32];
  int bx = blockIdx.x, by = blockIdx.y;
  xcd_swizzle(bx, by);
  const int m0 = bx * 128, n0 = by * 128;
  const int wave = threadIdx.x >> 6, lane = threadIdx.x & 63;
  const int wr = wave >> 1, wc = wave & 1;
  const int l15 = lane & 15, l4 = lane >> 4;

  f32x4 acc[4][4] = {};

  for (int kt = 0; kt < K; kt += 32) {
#pragma unroll
    for (int j = 0; j < 2; ++j) {
      const int c = threadIdx.x + j * 256;      // 0..511
      const int row = c >> 2, col8 = (c & 3) << 3;
      gload_lds16(A + (size_t)(m0 + row) * lda + kt + col8, As + c * 8);
      gload_lds16(B + (size_t)(n0 + row) * ldb + kt + col8, Bs + c * 8);
    }
    __syncthreads();
    bf16x8 af[4], bf[4];
#pragma unroll
    for (int ms = 0; ms < 4; ++ms)
      af[ms] = *(const bf16x8*)(As + (wr * 64 + ms * 16 + l15) * 32 + l4 * 8);
#pragma unroll
    for (int ns = 0; ns < 4; ++ns)
      bf[ns] = *(const bf16x8*)(Bs + (wc * 64 + ns * 16 + l15) * 32 + l4 * 8);
#pragma unroll
    for (int ms = 0; ms < 4; ++ms)
#pragma unroll
      for (int ns = 0; ns < 4; ++ns)
        acc[ms][ns] = __builtin_amdgcn_mfma_f32_16x16x32_bf16(af[ms], bf[ns], acc[ms][ns], 0, 0, 0);
    __syncthreads();
  }

  u16* Cb = (u16*)Cv + blockIdx.z * cZ;
  float* Cf = (float*)Cv + blockIdx.z * cZ;
#pragma unroll
  for (int ms = 0; ms < 4; ++ms)
#pragma unroll
    for (int i = 0; i < 4; ++i) {
      const int row = m0 + wr * 64 + ms * 16 + l4 * 4 + i;
#pragma unroll
      for (int ns = 0; ns < 4; ++ns) {
        const int col = n0 + wc * 64 + ns * 16 + l15;
        const size_t idx = (size_t)row * ldc + col;
        const float v = acc[ms][ns][i];
        if constexpr (EPI == 0) {
          Cb[idx] = f2b(v);
        } else if constexpr (EPI == 1) {
          const float g = b2f(Cb[idx]);
          Cb[idx] = f2b(g / (1.0f + __expf(-g)) * v);
        } else if constexpr (EPI == 2) {
          Cf[idx] = v + Res[idx];
        } else {
          Cf[idx] = v + Cf[idx];
        }
      }
    }
}

// ---------------------------------------------------------------- RoPE in place (q scaled 1/16) + V transpose -> vt (b,d,s)
__global__ __launch_bounds__(256) void rope_apply_kernel(u16* __restrict__ qkv,
                                                         const float* __restrict__ cosT,
                                                         const float* __restrict__ sinT,
                                                         u16* __restrict__ vt) {
  const int tok = blockIdx.x;
  const int b = tok >> 11, s = tok & 2047;
  u16* rowp = qkv + (size_t)tok * 2560;
  const float* ct = cosT + (size_t)tok * 128;
  const float* st = sinT + (size_t)tok * 128;
  for (int p = threadIdx.x; p < 1024; p += 256) {
    const int h = p >> 7, j = p & 127;
    u16* e = rowp + h * 256 + j;
    const float x1 = b2f(e[0]), x2 = b2f(e[128]);
    const float c = ct[j], sn = st[j];
    e[0]   = f2b((x1 * c - x2 * sn) * 0.0625f);
    e[128] = f2b((x2 * c + x1 * sn) * 0.0625f);
  }
  if (threadIdx.x < 128) {
    const int j = threadIdx.x;
    u16* e = rowp + 2048 + j;
    const float x1 = b2f(e[0]), x2 = b2f(e[128]);
    const float c = ct[j], sn = st[j];
    e[0]   = f2b(x1 * c - x2 * sn);
    e[128] = f2b(x2 * c + x1 * sn);
  }
  {
    const int d = threadIdx.x;
    vt[((size_t)b * HD_ + d) * SEQ + s] = rowp[2304 + d];
  }
}

// ---------------------------------------------------------------- row softmax, in place, 2048-wide bf16 rows
__global__ __launch_bounds__(256) void softmax_kernel(u16* __restrict__ Sb) {
  const int row = blockIdx.x;
  u16* rp = Sb + (size_t)row * 2048 + threadIdx.x * 8;
  const u16x8 t = *(const u16x8*)rp;
  float v[8];
#pragma unroll
  for (int j = 0; j < 8; ++j) v[j] = b2f(t[j]);
  float m = v[0];
#pragma unroll
  for (int j = 1; j < 8; ++j) m = fmaxf(m, v[j]);
  m = wmax(m);
  __shared__ float redm[4], reds[4];
  const int wave = threadIdx.x >> 6, lane = threadIdx.x & 63;
  if (lane == 0) redm[wave] = m;
  __syncthreads();
  m = fmaxf(fmaxf(redm[0], redm[1]), fmaxf(redm[2], redm[3]));
  float s = 0.f;
#pragma unroll
  for (int j = 0; j < 8; ++j) { v[j] = __expf(v[j] - m); s += v[j]; }
  s = wsum(s);
  if (lane == 0) reds[wave] = s;
  __syncthreads();
  const float inv = 1.0f / (reds[0] + reds[1] + reds[2] + reds[3]);
  u16x8 o;
#pragma unroll
  for (int j = 0; j < 8; ++j) o[j] = f2b(v[j] * inv);
  *(u16x8*)rp = o;
}

// ---------------------------------------------------------------- launch
extern "C" void kernel_launch(void* const* d_in, const int* in_sizes, int n_in,
                              void* d_out, int out_size, void* d_ws, size_t ws_size,
                              hipStream_t stream) {
  const float* x     = (const float*)d_in[0];
  const int*   pos   = (const int*)d_in[1];
  const float* temb  = (const float*)d_in[2];
  const float* ln1w  = (const float*)d_in[3];
  const float* ln1tw = (const float*)d_in[4];
  const float* ln2w  = (const float*)d_in[5];
  const float* ln2tw = (const float*)d_in[6];
  const float* Wq    = (const float*)d_in[7];
  const float* Wk    = (const float*)d_in[8];
  const float* Wv    = (const float*)d_in[9];
  const float* Wo    = (const float*)d_in[10];
  const float* Wg    = (const float*)d_in[11];
  const float* Wu    = (const float*)d_in[12];
  const float* Wd    = (const float*)d_in[13];
  float* out = (float*)d_out;      // fp32 output

  char* ws = (char*)d_ws;
  // ---- workspace layout (bytes); REQUIRED = 241,238,016 (230.06 MiB)
  constexpr size_t OFF_SF1  = 0;
  constexpr size_t OFF_SF2  = 32768;
  constexpr size_t OFF_COS  = 65536;
  constexpr size_t OFF_SIN  = 4259840;
  constexpr size_t OFF_WQKV = 8454144;
  constexpr size_t OFF_WO   = 18939904;
  constexpr size_t OFF_WG   = 27328512;
  constexpr size_t OFF_WU   = 60882944;
  constexpr size_t OFF_WD   = 94437376;
  constexpr size_t OFF_H    = 127991808;
  constexpr size_t OFF_QKV  = 161546240;   // inter aliases during MLP
  constexpr size_t OFF_VT   = 203489280;
  constexpr size_t OFF_CTX  = 207683584;
  constexpr size_t REQUIRED = 241238016;

  float* sf1 = (float*)(ws + OFF_SF1);
  float* sf2 = (float*)(ws + OFF_SF2);
  float* cosT = (float*)(ws + OFF_COS);
  float* sinT = (float*)(ws + OFF_SIN);
  u16* wqkv = (u16*)(ws + OFF_WQKV);
  u16* wo   = (u16*)(ws + OFF_WO);
  u16* wg   = (u16*)(ws + OFF_WG);
  u16* wu   = (u16*)(ws + OFF_WU);
  u16* wd   = (u16*)(ws + OFF_WD);
  u16* hbuf = (u16*)(ws + OFF_H);
  u16* qkv  = (u16*)(ws + OFF_QKV);
  u16* vt   = (u16*)(ws + OFF_VT);
  u16* ctx  = (u16*)(ws + OFF_CTX);
  u16* inter = (u16*)(ws + OFF_QKV);
  u16* Sbuf = (u16*)d_out;        // d_out (67.1 MB) is dead until step 6 == 8 heads x 2048^2 bf16

  if (ws_size < REQUIRED) return;

  auto cvt = [&](const float* s, u16* d, size_t n) {
    int n4 = (int)(n / 4);
    cvt_kernel<<<(n4 + 255) / 256, 256, 0, stream>>>(s, d, n4);
  };

  // 0) all weights -> bf16 once
  cvt(Wq, wqkv,                      (size_t)2048 * HID);
  cvt(Wk, wqkv + (size_t)2048 * HID, (size_t)256 * HID);
  cvt(Wv, wqkv + (size_t)2304 * HID, (size_t)256 * HID);
  cvt(Wo, wo, (size_t)HID * HID);
  cvt(Wg, wg, (size_t)INTER_ * HID);
  cvt(Wu, wu, (size_t)INTER_ * HID);
  cvt(Wd, wd, (size_t)HID * INTER_);

  // 1) adaptive scales + rope tables
  scale_kernel<<<(2 * BB * HID) / 4, 256, 0, stream>>>(temb, ln1w, ln1tw, ln2w, ln2tw, sf1, sf2);
  rope_table_kernel<<<(BB * SEQ * 128) / 256, 256, 0, stream>>>(pos, cosT, sinT);

  // 2) norm1 -> h (bf16)
  rmsnorm_kernel<<<BB * SEQ, 256, 0, stream>>>(x, sf1, hbuf);

  // 3) qkv = h @ Wqkv^T
  gemm_bt<0><<<dim3(64, 20), 256, 0, stream>>>(hbuf, wqkv, nullptr, qkv, HID, HID, HID, 2560, 0, 0);

  // 4) rope in place (q scaled 1/16), v -> vt
  rope_apply_kernel<<<BB * SEQ, 256, 0, stream>>>(qkv, cosT, sinT, vt);

  // 5) attention per batch: all 8 heads per launch (Sbuf = d_out scratch, 67MB)
  for (int b = 0; b < BB; ++b) {
    const u16* qb = qkv + (size_t)b * SEQ * 2560;          // head h at +h*256
    const u16* kb = qb + 2048;
    const u16* vb = vt + (size_t)b * HD_ * SEQ;
    u16* cb = ctx + (size_t)b * SEQ * HID;                 // head h at +h*256
    // S[h] = Q_h @ K^T  (scaled q already), 2048 blocks
    gemm_bt<0><<<dim3(16, 16, 8), 256, 0, stream>>>(
        qb, kb, nullptr, Sbuf, HD_, 2560, 2560, SEQ, (size_t)HD_, (size_t)SEQ * SEQ);
    // row softmax over all 8 heads
    softmax_kernel<<<NQH * SEQ, 256, 0, stream>>>(Sbuf);
    // ctx[h] = P @ V^T, 256 blocks
    gemm_bt<0><<<dim3(16, 2, 8), 256, 0, stream>>>(
        Sbuf, vb, nullptr, cb, SEQ, SEQ, SEQ, HID, (size_t)SEQ * SEQ, (size_t)HD_);
  }

  // 6) x2 = ctx @ Wo^T + x -> out (fp32, full overwrite of the Sbuf scratch)
  gemm_bt<2><<<dim3(64, 16), 256, 0, stream>>>(ctx, wo, x, out, HID, HID, HID, HID, 0, 0);

  // 7) norm2 -> h (reads fp32 x2)
  rmsnorm_kernel<<<BB * SEQ, 256, 0, stream>>>(out, sf2, hbuf);

  // 8) MLP, 4 chunks of M=2048 (inter aliases dead qkv)
  constexpr int MC = BB * SEQ / 4;
  for (int c = 0; c < 4; ++c) {
    const u16* hA = hbuf + (size_t)c * MC * HID;
    float* outC = out + (size_t)c * MC * HID;
    gemm_bt<0><<<dim3(MC / 128, INTER_ / 128), 256, 0, stream>>>(hA, wg, nullptr, inter, HID, HID, HID, INTER_, 0, 0);
    gemm_bt<1><<<dim3(MC / 128, INTER_ / 128), 256, 0, stream>>>(hA, wu, nullptr, inter, HID, HID, HID, INTER_, 0, 0);
    gemm_bt<3><<<dim3(MC / 128, HID / 128),    256, 0, stream>>>(inter, wd, nullptr, outC, INTER_, INTER_, INTER_, HID, 0, 0);
  }

  (void)in_sizes; (void)n_in; (void)out_size;
}

// Round 13
// 1964.818 us; speedup vs baseline: 1.7628x; 1.2642x over previous
//
#include <hip/hip_runtime.h>

typedef unsigned short u16;
typedef unsigned int   u32;
typedef __bf16  bf16x8 __attribute__((ext_vector_type(8)));
typedef float   f32x4  __attribute__((ext_vector_type(4)));
typedef u16     u16x4  __attribute__((ext_vector_type(4)));
typedef u16     u16x8  __attribute__((ext_vector_type(8)));

#define HID 2048
#define SEQ 2048
#define BB  4
#define NQH 8
#define HD_ 256
#define INTER_ 8192

__device__ __forceinline__ float b2f(u16 u) {
  union { float f; u32 i; } x; x.i = ((u32)u) << 16; return x.f;
}
__device__ __forceinline__ u16 f2b(float f) {
  u32 u = __float_as_uint(f);
  u32 r = u + 0x7fffu + ((u >> 16) & 1u);
  return (u16)(r >> 16);
}
__device__ __forceinline__ float wsum(float v) {
#pragma unroll
  for (int m = 1; m < 64; m <<= 1) v += __shfl_xor(v, m, 64);
  return v;
}
__device__ __forceinline__ float wmax(float v) {
#pragma unroll
  for (int m = 1; m < 64; m <<= 1) v = fmaxf(v, __shfl_xor(v, m, 64));
  return v;
}
__device__ __forceinline__ void gload_lds16(const void* gp, void* lp) {
  __builtin_amdgcn_global_load_lds(
      (const __attribute__((address_space(1))) void*)gp,
      (__attribute__((address_space(3))) void*)lp, 16, 0, 0);
}
// XCD-aware block swizzle (nwg % 8 == 0 on all our grids)
__device__ __forceinline__ void xcd_swizzle(int& bx, int& by) {
  const int nx = gridDim.x, ny = gridDim.y;
  const int nwg = nx * ny;
  if ((nwg & 7) == 0) {
    const int orig = by * nx + bx;
    const int q = nwg >> 3;
    const int wg = (orig & 7) * q + (orig >> 3);
    bx = wg % nx; by = wg / nx;
  }
}

// ---------------------------------------------------------------- fp32 -> bf16 convert
__global__ __launch_bounds__(256) void cvt_kernel(const float* __restrict__ src,
                                                  u16* __restrict__ dst, int n4) {
  int i = blockIdx.x * 256 + threadIdx.x;
  if (i < n4) {
    const float4 v = *(const float4*)(src + (size_t)i * 4);
    u16x4 o;
    o[0] = f2b(v.x); o[1] = f2b(v.y); o[2] = f2b(v.z); o[3] = f2b(v.w);
    *(u16x4*)(dst + (size_t)i * 4) = o;
  }
}

// ---------------------------------------------------------------- sfac[b][n] = w[n]*(1 + dot(t[b], tw[n]))
__global__ __launch_bounds__(256) void scale_kernel(
    const float* __restrict__ temb,
    const float* __restrict__ w1, const float* __restrict__ tw1,
    const float* __restrict__ w2, const float* __restrict__ tw2,
    float* __restrict__ sf1, float* __restrict__ sf2) {
  const int wave = threadIdx.x >> 6, lane = threadIdx.x & 63;
  const int o = blockIdx.x * 4 + wave;
  const int set = o / (BB * HID);
  const int r = o % (BB * HID);
  const int b = r / HID, n = r % HID;
  const float* tw = set ? tw2 : tw1;
  const float* w  = set ? w2  : w1;
  float* sf       = set ? sf2 : sf1;
  const float* tv  = temb + (size_t)b * HID;
  const float* twr = tw + (size_t)n * HID;
  float acc = 0.f;
#pragma unroll
  for (int q = 0; q < 8; ++q) {
    const float4 a = *(const float4*)(tv + q * 256 + lane * 4);
    const float4 c = *(const float4*)(twr + q * 256 + lane * 4);
    acc += a.x * c.x + a.y * c.y + a.z * c.z + a.w * c.w;
  }
  acc = wsum(acc);
  if (lane == 0) sf[(size_t)b * HID + n] = w[n] * (1.0f + acc);
}

// ---------------------------------------------------------------- rope tables
__global__ __launch_bounds__(256) void rope_table_kernel(const int* __restrict__ pos_ids,
                                                         float* __restrict__ cosT,
                                                         float* __restrict__ sinT) {
  const int idx = blockIdx.x * 256 + threadIdx.x;   // B*S*128
  const int j = idx & 127, bs = idx >> 7;
  const float pos = (float)pos_ids[bs];
  const float inv = exp2f(-(float)j * (13.287712379549449f / 128.0f)); // 10000^{-j/128}
  const float ang = pos * inv;
  float sv, cv;
  sincosf(ang, &sv, &cv);
  cosT[idx] = cv; sinT[idx] = sv;
}

// ---------------------------------------------------------------- AdaRMS: bf16 out = fp32 in * rsqrt(mean sq) * sfac
__global__ __launch_bounds__(256) void rmsnorm_kernel(const float* __restrict__ xin,
                                                      const float* __restrict__ sfac,
                                                      u16* __restrict__ out) {
  const int row = blockIdx.x;
  const int b = row >> 11;
  const float* xr = xin + (size_t)row * HID + threadIdx.x * 8;
  const float4 v0 = *(const float4*)(xr);
  const float4 v1 = *(const float4*)(xr + 4);
  float v[8] = {v0.x, v0.y, v0.z, v0.w, v1.x, v1.y, v1.z, v1.w};
  float ss = 0.f;
#pragma unroll
  for (int j = 0; j < 8; ++j) ss += v[j] * v[j];
  ss = wsum(ss);
  __shared__ float red[4];
  const int wave = threadIdx.x >> 6, lane = threadIdx.x & 63;
  if (lane == 0) red[wave] = ss;
  __syncthreads();
  const float tot = red[0] + red[1] + red[2] + red[3];
  const float rs = rsqrtf(tot * (1.0f / HID) + 1e-6f);
  const float* sf = sfac + (size_t)b * HID + threadIdx.x * 8;
  u16* op = out + (size_t)row * HID + threadIdx.x * 8;
  u16x8 o;
#pragma unroll
  for (int j = 0; j < 8; ++j) o[j] = f2b(v[j] * rs * sf[j]);
  *(u16x8*)op = o;
}

// ---------------------------------------------------------------- MFMA GEMM: C(MxN) = A(MxK) @ B(NxK)^T, bf16 in, fp32 acc
// 128x128 tile, BK=32, 4 waves (2x2), global_load_lds width-16 staging,
// 2-PHASE DOUBLE-BUFFER: stage(next) issued after the barrier, waited at the NEXT
// barrier -> staging latency hides under ds_read+MFMA of the current tile.
// XCD-aware block swizzle. blockIdx.z offsets A by aZ, C by cZ elements.
// EPI: 0 = bf16 store; 1 = bf16 C := silu(C_old)*acc (in place);
//      2 = FP32 store acc + Res_f32[idx]; 3 = FP32 C := acc + C_old (in place residual)
template <int EPI>
__global__ __launch_bounds__(256) void gemm_bt(const u16* __restrict__ A,
                                               const u16* __restrict__ B,
                                               const float* __restrict__ Res,
                                               void* __restrict__ Cv,
                                               int K, int lda, int ldb, int ldc,
                                               size_t aZ, size_t cZ) {
  A += blockIdx.z * aZ;
  __shared__ u16 As[2][128 * 32];
  __shared__ u16 Bs[2][128 * 32];
  int bx = blockIdx.x, by = blockIdx.y;
  xcd_swizzle(bx, by);
  const int m0 = bx * 128, n0 = by * 128;
  const int wave = threadIdx.x >> 6, lane = threadIdx.x & 63;
  const int wr = wave >> 1, wc = wave & 1;
  const int l15 = lane & 15, l4 = lane >> 4;

  auto stage = [&](int buf, int kt) {
#pragma unroll
    for (int j = 0; j < 2; ++j) {
      const int c = threadIdx.x + j * 256;      // 0..511
      const int row = c >> 2, col8 = (c & 3) << 3;
      gload_lds16(A + (size_t)(m0 + row) * lda + kt + col8, &As[buf][c * 8]);
      gload_lds16(B + (size_t)(n0 + row) * ldb + kt + col8, &Bs[buf][c * 8]);
    }
  };

  f32x4 acc[4][4] = {};

  stage(0, 0);
  int cur = 0;
  for (int kt = 0; kt < K; kt += 32) {
    __syncthreads();                 // vmcnt(0)+lgkmcnt(0) drain: stage(cur) landed, prev reads done
    if (kt + 32 < K) stage(cur ^ 1, kt + 32);   // async next tile; waited at NEXT barrier
    bf16x8 af[4], bf[4];
#pragma unroll
    for (int ms = 0; ms < 4; ++ms)
      af[ms] = *(const bf16x8*)(&As[cur][(wr * 64 + ms * 16 + l15) * 32 + l4 * 8]);
#pragma unroll
    for (int ns = 0; ns < 4; ++ns)
      bf[ns] = *(const bf16x8*)(&Bs[cur][(wc * 64 + ns * 16 + l15) * 32 + l4 * 8]);
#pragma unroll
    for (int ms = 0; ms < 4; ++ms)
#pragma unroll
      for (int ns = 0; ns < 4; ++ns)
        acc[ms][ns] = __builtin_amdgcn_mfma_f32_16x16x32_bf16(af[ms], bf[ns], acc[ms][ns], 0, 0, 0);
    cur ^= 1;
  }

  u16* Cb = (u16*)Cv + blockIdx.z * cZ;
  float* Cf = (float*)Cv + blockIdx.z * cZ;
#pragma unroll
  for (int ms = 0; ms < 4; ++ms)
#pragma unroll
    for (int i = 0; i < 4; ++i) {
      const int row = m0 + wr * 64 + ms * 16 + l4 * 4 + i;
#pragma unroll
      for (int ns = 0; ns < 4; ++ns) {
        const int col = n0 + wc * 64 + ns * 16 + l15;
        const size_t idx = (size_t)row * ldc + col;
        const float v = acc[ms][ns][i];
        if constexpr (EPI == 0) {
          Cb[idx] = f2b(v);
        } else if constexpr (EPI == 1) {
          const float g = b2f(Cb[idx]);
          Cb[idx] = f2b(g / (1.0f + __expf(-g)) * v);
        } else if constexpr (EPI == 2) {
          Cf[idx] = v + Res[idx];
        } else {
          Cf[idx] = v + Cf[idx];
        }
      }
    }
}

// ---------------------------------------------------------------- RoPE in place (q scaled 1/16) + V transpose -> vt (b,d,s)
__global__ __launch_bounds__(256) void rope_apply_kernel(u16* __restrict__ qkv,
                                                         const float* __restrict__ cosT,
                                                         const float* __restrict__ sinT,
                                                         u16* __restrict__ vt) {
  const int tok = blockIdx.x;
  const int b = tok >> 11, s = tok & 2047;
  u16* rowp = qkv + (size_t)tok * 2560;
  const float* ct = cosT + (size_t)tok * 128;
  const float* st = sinT + (size_t)tok * 128;
  for (int p = threadIdx.x; p < 1024; p += 256) {
    const int h = p >> 7, j = p & 127;
    u16* e = rowp + h * 256 + j;
    const float x1 = b2f(e[0]), x2 = b2f(e[128]);
    const float c = ct[j], sn = st[j];
    e[0]   = f2b((x1 * c - x2 * sn) * 0.0625f);
    e[128] = f2b((x2 * c + x1 * sn) * 0.0625f);
  }
  if (threadIdx.x < 128) {
    const int j = threadIdx.x;
    u16* e = rowp + 2048 + j;
    const float x1 = b2f(e[0]), x2 = b2f(e[128]);
    const float c = ct[j], sn = st[j];
    e[0]   = f2b(x1 * c - x2 * sn);
    e[128] = f2b(x2 * c + x1 * sn);
  }
  {
    const int d = threadIdx.x;
    vt[((size_t)b * HD_ + d) * SEQ + s] = rowp[2304 + d];
  }
}

// ---------------------------------------------------------------- row softmax, in place, 2048-wide bf16 rows
__global__ __launch_bounds__(256) void softmax_kernel(u16* __restrict__ Sb) {
  const int row = blockIdx.x;
  u16* rp = Sb + (size_t)row * 2048 + threadIdx.x * 8;
  const u16x8 t = *(const u16x8*)rp;
  float v[8];
#pragma unroll
  for (int j = 0; j < 8; ++j) v[j] = b2f(t[j]);
  float m = v[0];
#pragma unroll
  for (int j = 1; j < 8; ++j) m = fmaxf(m, v[j]);
  m = wmax(m);
  __shared__ float redm[4], reds[4];
  const int wave = threadIdx.x >> 6, lane = threadIdx.x & 63;
  if (lane == 0) redm[wave] = m;
  __syncthreads();
  m = fmaxf(fmaxf(redm[0], redm[1]), fmaxf(redm[2], redm[3]));
  float s = 0.f;
#pragma unroll
  for (int j = 0; j < 8; ++j) { v[j] = __expf(v[j] - m); s += v[j]; }
  s = wsum(s);
  if (lane == 0) reds[wave] = s;
  __syncthreads();
  const float inv = 1.0f / (reds[0] + reds[1] + reds[2] + reds[3]);
  u16x8 o;
#pragma unroll
  for (int j = 0; j < 8; ++j) o[j] = f2b(v[j] * inv);
  *(u16x8*)rp = o;
}

// ---------------------------------------------------------------- launch
extern "C" void kernel_launch(void* const* d_in, const int* in_sizes, int n_in,
                              void* d_out, int out_size, void* d_ws, size_t ws_size,
                              hipStream_t stream) {
  const float* x     = (const float*)d_in[0];
  const int*   pos   = (const int*)d_in[1];
  const float* temb  = (const float*)d_in[2];
  const float* ln1w  = (const float*)d_in[3];
  const float* ln1tw = (const float*)d_in[4];
  const float* ln2w  = (const float*)d_in[5];
  const float* ln2tw = (const float*)d_in[6];
  const float* Wq    = (const float*)d_in[7];
  const float* Wk    = (const float*)d_in[8];
  const float* Wv    = (const float*)d_in[9];
  const float* Wo    = (const float*)d_in[10];
  const float* Wg    = (const float*)d_in[11];
  const float* Wu    = (const float*)d_in[12];
  const float* Wd    = (const float*)d_in[13];
  float* out = (float*)d_out;      // fp32 output

  char* ws = (char*)d_ws;
  // ---- workspace layout (bytes); REQUIRED = 241,238,016 (230.06 MiB, proven)
  constexpr size_t OFF_SF1  = 0;
  constexpr size_t OFF_SF2  = 32768;
  constexpr size_t OFF_COS  = 65536;
  constexpr size_t OFF_SIN  = 4259840;
  constexpr size_t OFF_WQKV = 8454144;
  constexpr size_t OFF_WO   = 18939904;
  constexpr size_t OFF_WG   = 27328512;
  constexpr size_t OFF_WU   = 60882944;
  constexpr size_t OFF_WD   = 94437376;
  constexpr size_t OFF_H    = 127991808;
  constexpr size_t OFF_QKV  = 161546240;   // MLP phase: inter (67.1MB, M=4096 chunk) aliases qkv+vt+ctx
  constexpr size_t OFF_VT   = 203489280;
  constexpr size_t OFF_CTX  = 207683584;
  constexpr size_t REQUIRED = 241238016;

  float* sf1 = (float*)(ws + OFF_SF1);
  float* sf2 = (float*)(ws + OFF_SF2);
  float* cosT = (float*)(ws + OFF_COS);
  float* sinT = (float*)(ws + OFF_SIN);
  u16* wqkv = (u16*)(ws + OFF_WQKV);
  u16* wo   = (u16*)(ws + OFF_WO);
  u16* wg   = (u16*)(ws + OFF_WG);
  u16* wu   = (u16*)(ws + OFF_WU);
  u16* wd   = (u16*)(ws + OFF_WD);
  u16* hbuf = (u16*)(ws + OFF_H);
  u16* qkv  = (u16*)(ws + OFF_QKV);
  u16* vt   = (u16*)(ws + OFF_VT);
  u16* ctx  = (u16*)(ws + OFF_CTX);
  u16* inter = (u16*)(ws + OFF_QKV);       // 4096 x 8192 bf16 chunk
  u16* Sbuf = (u16*)d_out;                 // d_out (67.1 MB) dead until step 6

  if (ws_size < REQUIRED) return;

  auto cvt = [&](const float* s, u16* d, size_t n) {
    int n4 = (int)(n / 4);
    cvt_kernel<<<(n4 + 255) / 256, 256, 0, stream>>>(s, d, n4);
  };

  // 0) all weights -> bf16 once
  cvt(Wq, wqkv,                      (size_t)2048 * HID);
  cvt(Wk, wqkv + (size_t)2048 * HID, (size_t)256 * HID);
  cvt(Wv, wqkv + (size_t)2304 * HID, (size_t)256 * HID);
  cvt(Wo, wo, (size_t)HID * HID);
  cvt(Wg, wg, (size_t)INTER_ * HID);
  cvt(Wu, wu, (size_t)INTER_ * HID);
  cvt(Wd, wd, (size_t)HID * INTER_);

  // 1) adaptive scales + rope tables
  scale_kernel<<<(2 * BB * HID) / 4, 256, 0, stream>>>(temb, ln1w, ln1tw, ln2w, ln2tw, sf1, sf2);
  rope_table_kernel<<<(BB * SEQ * 128) / 256, 256, 0, stream>>>(pos, cosT, sinT);

  // 2) norm1 -> h (bf16)
  rmsnorm_kernel<<<BB * SEQ, 256, 0, stream>>>(x, sf1, hbuf);

  // 3) qkv = h @ Wqkv^T
  gemm_bt<0><<<dim3(64, 20), 256, 0, stream>>>(hbuf, wqkv, nullptr, qkv, HID, HID, HID, 2560, 0, 0);

  // 4) rope in place (q scaled 1/16), v -> vt
  rope_apply_kernel<<<BB * SEQ, 256, 0, stream>>>(qkv, cosT, sinT, vt);

  // 5) attention per batch: all 8 heads per launch (Sbuf = d_out scratch)
  for (int b = 0; b < BB; ++b) {
    const u16* qb = qkv + (size_t)b * SEQ * 2560;          // head h at +h*256
    const u16* kb = qb + 2048;
    const u16* vb = vt + (size_t)b * HD_ * SEQ;
    u16* cb = ctx + (size_t)b * SEQ * HID;                 // head h at +h*256
    gemm_bt<0><<<dim3(16, 16, 8), 256, 0, stream>>>(
        qb, kb, nullptr, Sbuf, HD_, 2560, 2560, SEQ, (size_t)HD_, (size_t)SEQ * SEQ);
    softmax_kernel<<<NQH * SEQ, 256, 0, stream>>>(Sbuf);
    gemm_bt<0><<<dim3(16, 2, 8), 256, 0, stream>>>(
        Sbuf, vb, nullptr, cb, SEQ, SEQ, SEQ, HID, (size_t)SEQ * SEQ, (size_t)HD_);
  }

  // 6) x2 = ctx @ Wo^T + x -> out (fp32, full overwrite of the Sbuf scratch)
  gemm_bt<2><<<dim3(64, 16), 256, 0, stream>>>(ctx, wo, x, out, HID, HID, HID, HID, 0, 0);

  // 7) norm2 -> h (reads fp32 x2)
  rmsnorm_kernel<<<BB * SEQ, 256, 0, stream>>>(out, sf2, hbuf);

  // 8) MLP, 2 chunks of M=4096 (inter aliases dead qkv/vt/ctx)
  constexpr int MC = BB * SEQ / 2;   // 4096
  for (int c = 0; c < 2; ++c) {
    const u16* hA = hbuf + (size_t)c * MC * HID;
    float* outC = out + (size_t)c * MC * HID;
    gemm_bt<0><<<dim3(MC / 128, INTER_ / 128), 256, 0, stream>>>(hA, wg, nullptr, inter, HID, HID, HID, INTER_, 0, 0);
    gemm_bt<1><<<dim3(MC / 128, INTER_ / 128), 256, 0, stream>>>(hA, wu, nullptr, inter, HID, HID, HID, INTER_, 0, 0);
    gemm_bt<3><<<dim3(MC / 128, HID / 128),    256, 0, stream>>>(inter, wd, nullptr, outC, INTER_, INTER_, INTER_, HID, 0, 0);
  }

  (void)in_sizes; (void)n_in; (void)out_size;
}